// Round 3
// baseline (417.929 us; speedup 1.0000x reference)
//
#include <hip/hip_runtime.h>
#include <hip/hip_bf16.h>

typedef __bf16 bf16x8 __attribute__((ext_vector_type(8)));
typedef __bf16 bf16x4 __attribute__((ext_vector_type(4)));
typedef float  f32x4  __attribute__((ext_vector_type(4)));

#define MFMA16(a,b,c) __builtin_amdgcn_mfma_f32_16x16x32_bf16((a),(b),(c),0,0,0)

constexpr int Bb = 2048, Tt = 80, Ee = 100, Uu = 256;
constexpr int BM = 8;          // batch rows per rnn block
constexpr int RNT = 256;       // rnn: 4 waves
constexpr int PGT = 512;       // pregemm: 8 waves
constexpr int HCH = 256;       // elems per k-chunk (32 k x 8 rows)
constexpr int HB = 8 * HCH;    // one h buffer

template<bool ISBF>
__device__ __forceinline__ float ldf(const void* p, int i) {
  if constexpr (ISBF) return (float)((const __bf16*)p)[i];
  else                return ((const float*)p)[i];
}

__device__ __forceinline__ float fast_tanh(float x) {
  float e = __expf(2.f * x);
  return 1.f - 2.f / (e + 1.f);
}

__global__ void detect_kernel(const void* wh, int* flag) {
  __shared__ int cnt;
  if (threadIdx.x == 0) cnt = 0;
  __syncthreads();
  const unsigned short* u = (const unsigned short*)wh;
  int c = 0;
  for (int i = threadIdx.x; i < 256; i += 64) {
    unsigned short h = u[2 * i];
    int ex = (h >> 7) & 0xFF;
    if (ex >= 135 || (ex >= 1 && ex <= 95)) c++;
  }
  atomicAdd(&cnt, c);
  __syncthreads();
  if (threadIdx.x == 0) *flag = (cnt < 64) ? 1 : 0;
}

// ---------------- pre-GEMM -------------------------------------------------
// U layout: U[t][rb][tid32][16] bf16, tid32 = wv*32 + (lane&31) of the rnn
// block rb (8 batch rows). slot = e*4 + i: e = n-tile within wave (4 tiles of
// 16 cols), i = acc reg. bias0 pre-folded. Block: 16 b-rows x 8 t = 128 GEMM
// rows x 256 cols, staged through LDS for coalesced output.
template<bool ISBF>
__launch_bounds__(PGT, 1)
__global__ void pregemm_kernel(const int* __restrict__ tokens,
                               const void* __restrict__ emb,
                               const void* __restrict__ Wx0,
                               const void* __restrict__ bias,
                               __bf16* __restrict__ U,
                               const int* __restrict__ flag) {
  if ((*flag != 0) != ISBF) return;
  __shared__ __align__(16) __bf16 sA[8 * 4 * 64 * 8];   // 32 KB A-frags
  __shared__ __align__(16) __bf16 lout[32768];          // 64 KB out tile

  const int tid = threadIdx.x, lane = tid & 63, wv = tid >> 6;
  const int m = lane & 15, kc = lane >> 4;
  const int g = blockIdx.x / 10, tc = blockIdx.x % 10;
  const int B0 = g * 16, T0 = tc * 8;

  // stage A tile: row r -> (b = B0 + (r>>3), t = T0 + (r&7)), K padded 100->128
  for (int q = tid; q < 128 * 32; q += PGT) {
    int r = q >> 5, c = (q & 31) * 4;
    int tok = tokens[(B0 + (r >> 3)) * Tt + T0 + (r & 7)];
    float v0 = 0.f, v1 = 0.f, v2 = 0.f, v3 = 0.f;
    if (c < Ee) {
      if constexpr (ISBF) {
        bf16x4 t4 = *(const bf16x4*)((const __bf16*)emb + tok * Ee + c);
        v0 = (float)t4[0]; v1 = (float)t4[1]; v2 = (float)t4[2]; v3 = (float)t4[3];
      } else {
        f32x4 t4 = *(const f32x4*)((const float*)emb + tok * Ee + c);
        v0 = t4[0]; v1 = t4[1]; v2 = t4[2]; v3 = t4[3];
      }
    }
    __bf16* p = sA + (((r >> 4) * 4 + (c >> 5)) * 64 + ((c >> 3) & 3) * 16 + (r & 15)) * 8 + (c & 7);
    p[0] = (__bf16)v0; p[1] = (__bf16)v1; p[2] = (__bf16)v2; p[3] = (__bf16)v3;
  }

  bf16x8 fB[2][4];
  float bs[2];
  #pragma unroll
  for (int e = 0; e < 2; ++e) {
    const int col = wv * 32 + e * 16 + m;
    bs[e] = ldf<ISBF>(bias, col);
    #pragma unroll
    for (int s = 0; s < 4; ++s) {
      bf16x8 tr;
      #pragma unroll
      for (int j = 0; j < 8; ++j) {
        int k = s * 32 + kc * 8 + j;
        tr[j] = (k < Ee) ? (__bf16)ldf<ISBF>(Wx0, k * Uu + col) : (__bf16)0.f;
      }
      fB[e][s] = tr;
    }
  }
  __syncthreads();

  const int au = (kc * 16 + m) * 8;
  const int lr3 = lane >> 5;                 // (row>>3) within 16-row tile
  const int tb = ((lane >> 4) & 1) * 4;      // t_l = tb + ii
  #pragma unroll
  for (int mt = 0; mt < 8; ++mt) {
    f32x4 a0 = {0.f,0.f,0.f,0.f}, a1 = {0.f,0.f,0.f,0.f};
    #pragma unroll
    for (int s = 0; s < 4; ++s) {
      bf16x8 a = *(const bf16x8*)(sA + (mt * 4 + s) * 512 + au);
      a0 = MFMA16(a, fB[0][s], a0);
      a1 = MFMA16(a, fB[1][s], a1);
    }
    int rr = mt * 2 + lr3;                   // global b-row>>3 within block
    int rb_l = rr >> 3, r8 = rr & 7;
    int lane32 = ((r8 >> 2) << 4) + m;
    int i = r8 & 3;
    int e0 = (wv & 1) * 2;                   // rnn e index of first tile
    #pragma unroll
    for (int ii = 0; ii < 4; ++ii) {
      int base = (((tb + ii) * 2 + rb_l) * 128 + (wv >> 1) * 32 + lane32) * 16 + i;
      lout[base + e0 * 4]       = (__bf16)(a0[ii] + bs[0]);
      lout[base + (e0 + 1) * 4] = (__bf16)(a1[ii] + bs[1]);
    }
  }
  __syncthreads();

  // coalesced copy-out: 16 planes of 2048 elems -> U[t][rb][...]
  for (int it = 0; it < 8; ++it) {
    int idx = (it * PGT + tid) * 8;
    int p = idx >> 11, w = idx & 2047;
    int t_l = p >> 1, rb_l = p & 1;
    size_t dst = ((size_t)((T0 + t_l) * 256 + (g * 2 + rb_l))) * 2048 + w;
    *(bf16x8*)(U + dst) = *(const bf16x8*)(lout + idx);
  }
}

// ---------------- persistent 2-layer RNN scan ------------------------------
// 4 waves x 64 cols each. h in LDS A-frag order; lanes m>=8 broadcast-read
// rows m-8 (free 2-way alias); garbage C rows 8..15 discarded (lanes>=32).
template<bool ISBF>
__launch_bounds__(RNT, 1)
__global__ void rnn_kernel(const void* __restrict__ Wx1,
                           const void* __restrict__ Wh,
                           const void* __restrict__ bias,
                           const void* __restrict__ h0g,
                           const void* __restrict__ Wo,
                           const void* __restrict__ bo,
                           const __bf16* __restrict__ U,
                           void* __restrict__ out,
                           const int* __restrict__ flag) {
  if ((*flag != 0) != ISBF) return;

  __shared__ __align__(16) __bf16 s_h0[2 * HB];
  __shared__ __align__(16) __bf16 s_h1[2 * HB];

  const int tid = threadIdx.x, lane = tid & 63, wv = tid >> 6;  // wv 0..3
  const int m = lane & 15, kc = lane >> 4;
  const int rb = blockIdx.x, b0 = rb * BM;
  const int au = (kc * 8 + (m & 7)) * 8;

  for (int idx = tid; idx < BM * Uu; idx += RNT) {
    int r = idx >> 8, c = idx & 255;
    int off = (c >> 5) * HCH + (((c >> 3) & 3) * 8 + r) * 8 + (c & 7);
    s_h0[off] = (__bf16)ldf<ISBF>(h0g, (b0 + r) * Uu + c);
    s_h1[off] = (__bf16)ldf<ISBF>(h0g, Bb * Uu + (b0 + r) * Uu + c);
  }

  bf16x8 fWh0[4][8], fWx1[4][8], fWh1[4][8];
  float b1v[4];
  #pragma unroll
  for (int e = 0; e < 4; ++e) {
    const int col = (wv * 4 + e) * 16 + m;
    b1v[e] = ldf<ISBF>(bias, Uu + col);
    #pragma unroll
    for (int s = 0; s < 8; ++s) {
      const int kb = s * 32 + kc * 8;
      bf16x8 t0, t1, t2;
      #pragma unroll
      for (int j = 0; j < 8; ++j) {
        t0[j] = (__bf16)ldf<ISBF>(Wh,  (kb + j) * Uu + col);
        t1[j] = (__bf16)ldf<ISBF>(Wx1, (kb + j) * Uu + col);
        t2[j] = (__bf16)ldf<ISBF>(Wh,  Uu * Uu + (kb + j) * Uu + col);
      }
      fWh0[e][s] = t0; fWx1[e][s] = t1; fWh1[e][s] = t2;
    }
  }

  const int tid32 = wv * 32 + (lane & 31);
  const int j2 = lane & 7, kc2 = m >> 3, rb2 = (lane >> 4) * 4;

  const __bf16* Ucur = U + ((size_t)(0 * 256 + rb) * 128 + tid32) * 16;
  bf16x8 u0 = *(const bf16x8*)Ucur;        // slots 0..7 (e=0,1); u1 L1-hits later

  __syncthreads();

  for (int t = 0; t < Tt; ++t) {
    const int p = t & 1, pn = p ^ 1;

    // ---- phase A: h0' = tanh(u_t + h0@Wh0) (bias0 folded into u) ----
    bf16x8 u1 = *(const bf16x8*)(Ucur + 8); // same cache lines as u0 prefetch
    f32x4 aA[4];
    aA[0] = (f32x4){(float)u0[0], (float)u0[1], (float)u0[2], (float)u0[3]};
    aA[1] = (f32x4){(float)u0[4], (float)u0[5], (float)u0[6], (float)u0[7]};
    aA[2] = (f32x4){(float)u1[0], (float)u1[1], (float)u1[2], (float)u1[3]};
    aA[3] = (f32x4){(float)u1[4], (float)u1[5], (float)u1[6], (float)u1[7]};
    {
      const __bf16* hb = s_h0 + p * HB + au;
      #pragma unroll
      for (int s = 0; s < 8; ++s) {
        bf16x8 a = *(const bf16x8*)(hb + s * HCH);
        aA[0] = MFMA16(a, fWh0[0][s], aA[0]);
        aA[1] = MFMA16(a, fWh0[1][s], aA[1]);
        aA[2] = MFMA16(a, fWh0[2][s], aA[2]);
        aA[3] = MFMA16(a, fWh0[3][s], aA[3]);
      }
    }
    if (lane < 32) {
      #pragma unroll
      for (int e = 0; e < 4; ++e) {
        __bf16* wp = s_h0 + pn * HB + ((wv * 4 + e) >> 1) * HCH
                   + (((e & 1) * 2 + kc2) * 8 + rb2) * 8 + j2;
        #pragma unroll
        for (int ii = 0; ii < 4; ++ii)
          wp[ii * 8] = (__bf16)fast_tanh(aA[e][ii]);
      }
    }
    __syncthreads();

    // prefetch u_{t+1}: phase-B window covers the latency
    {
      int tn = (t + 1 < Tt) ? t + 1 : Tt - 1;
      Ucur = U + ((size_t)(tn * 256 + rb) * 128 + tid32) * 16;
      u0 = *(const bf16x8*)Ucur;
    }

    // ---- phase B: h1' = tanh(h0'@Wx1 + h1@Wh1 + b1), 8 acc chains ----
    f32x4 bA[4] = {{0.f,0.f,0.f,0.f},{0.f,0.f,0.f,0.f},{0.f,0.f,0.f,0.f},{0.f,0.f,0.f,0.f}};
    f32x4 cA[4] = {{0.f,0.f,0.f,0.f},{0.f,0.f,0.f,0.f},{0.f,0.f,0.f,0.f},{0.f,0.f,0.f,0.f}};
    {
      const __bf16* h0n = s_h0 + pn * HB + au;
      const __bf16* h1b = s_h1 + p * HB + au;
      #pragma unroll
      for (int s = 0; s < 8; ++s) {
        bf16x8 a  = *(const bf16x8*)(h0n + s * HCH);
        bf16x8 a2 = *(const bf16x8*)(h1b + s * HCH);
        bA[0] = MFMA16(a,  fWx1[0][s], bA[0]);
        bA[1] = MFMA16(a,  fWx1[1][s], bA[1]);
        bA[2] = MFMA16(a,  fWx1[2][s], bA[2]);
        bA[3] = MFMA16(a,  fWx1[3][s], bA[3]);
        cA[0] = MFMA16(a2, fWh1[0][s], cA[0]);
        cA[1] = MFMA16(a2, fWh1[1][s], cA[1]);
        cA[2] = MFMA16(a2, fWh1[2][s], cA[2]);
        cA[3] = MFMA16(a2, fWh1[3][s], cA[3]);
      }
    }
    if (lane < 32) {
      #pragma unroll
      for (int e = 0; e < 4; ++e) {
        __bf16* wp = s_h1 + pn * HB + ((wv * 4 + e) >> 1) * HCH
                   + (((e & 1) * 2 + kc2) * 8 + rb2) * 8 + j2;
        #pragma unroll
        for (int ii = 0; ii < 4; ++ii)
          wp[ii * 8] = (__bf16)fast_tanh(bA[e][ii] + cA[e][ii] + b1v[e]);
      }
    }
    __syncthreads();
  }

  // ---- epilogue: sigmoid(h1 @ Wo + bo); final h1 at parity 0 ----
  {
    const int r = tid >> 5, q = tid & 31;
    const __bf16* hp = s_h1 + (q >> 2) * HCH + ((q & 3) * 8 + r) * 8;
    bf16x8 hv = *(const bf16x8*)hp;
    float part = 0.f;
    #pragma unroll
    for (int j = 0; j < 8; ++j) part += (float)hv[j] * ldf<ISBF>(Wo, q * 8 + j);
    #pragma unroll
    for (int o = 16; o >= 1; o >>= 1) part += __shfl_down(part, o, 32);
    if (q == 0) {
      float z = part + ldf<ISBF>(bo, 0);
      float sg = 1.f / (1.f + __expf(-z));
      if constexpr (ISBF) ((__bf16*)out)[b0 + r] = (__bf16)sg;
      else                ((float*)out)[b0 + r]  = sg;
    }
  }
}

extern "C" void kernel_launch(void* const* d_in, const int* in_sizes, int n_in,
                              void* d_out, int out_size, void* d_ws, size_t ws_size,
                              hipStream_t stream) {
  const int*  tokens = (const int*)d_in[0];
  const void* emb = d_in[1];
  const void* Wx0 = d_in[2];
  const void* Wx1 = d_in[3];
  const void* Wh  = d_in[4];
  const void* b   = d_in[5];
  const void* h0  = d_in[6];
  const void* Wo  = d_in[7];
  const void* bo  = d_in[8];

  int* flag = (int*)d_ws;
  __bf16* U = (__bf16*)((char*)d_ws + 256);
  const size_t needU = 256 + (size_t)Tt * 256 * 128 * 16 * sizeof(__bf16);  // ~80 MB
  if (ws_size < needU) return;  // R2 confirmed ws_size is sufficient on this harness

  detect_kernel<<<1, 64, 0, stream>>>(Wh, flag);
  pregemm_kernel<true ><<<dim3(128 * 10), dim3(PGT), 0, stream>>>(tokens, emb, Wx0, b, U, flag);
  pregemm_kernel<false><<<dim3(128 * 10), dim3(PGT), 0, stream>>>(tokens, emb, Wx0, b, U, flag);
  rnn_kernel<true ><<<dim3(Bb / BM), dim3(RNT), 0, stream>>>(Wx1, Wh, b, h0, Wo, bo, U, d_out, flag);
  rnn_kernel<false><<<dim3(Bb / BM), dim3(RNT), 0, stream>>>(Wx1, Wh, b, h0, Wo, bo, U, d_out, flag);
}

// Round 4
// 350.325 us; speedup vs baseline: 1.1930x; 1.1930x over previous
//
#include <hip/hip_runtime.h>
#include <hip/hip_bf16.h>

typedef __bf16 bf16x8 __attribute__((ext_vector_type(8)));
typedef __bf16 bf16x4 __attribute__((ext_vector_type(4)));
typedef float  f32x4  __attribute__((ext_vector_type(4)));

#define MFMA16(a,b,c) __builtin_amdgcn_mfma_f32_16x16x32_bf16((a),(b),(c),0,0,0)

constexpr int Bb = 2048, Tt = 80, Ee = 100, Uu = 256;
constexpr int BM = 8;          // batch rows per rnn block
constexpr int RNT = 512;       // rnn: 8 waves
constexpr int PGT = 512;       // pregemm: 8 waves
constexpr int HCH = 256;       // elems per k-chunk (32 k x 8 rows)
constexpr int HB = 8 * HCH;    // one h buffer

template<bool ISBF>
__device__ __forceinline__ float ldf(const void* p, int i) {
  if constexpr (ISBF) return (float)((const __bf16*)p)[i];
  else                return ((const float*)p)[i];
}

__device__ __forceinline__ float fast_tanh(float x) {
  float e = __expf(2.f * x);
  return 1.f - 2.f / (e + 1.f);
}

__global__ void detect_kernel(const void* wh, int* flag) {
  __shared__ int cnt;
  if (threadIdx.x == 0) cnt = 0;
  __syncthreads();
  const unsigned short* u = (const unsigned short*)wh;
  int c = 0;
  for (int i = threadIdx.x; i < 256; i += 64) {
    unsigned short h = u[2 * i];
    int ex = (h >> 7) & 0xFF;
    if (ex >= 135 || (ex >= 1 && ex <= 95)) c++;
  }
  atomicAdd(&cnt, c);
  __syncthreads();
  if (threadIdx.x == 0) *flag = (cnt < 64) ? 1 : 0;
}

// ---------------- pre-GEMM (unchanged from R3 — known-good) ----------------
// U layout: U[t][rb][tid32][16] bf16; slot = e*4+i where (row = ((tid32>>4)&1)*4+i,
// col = (tid32>>5)*64 + e*16 + (tid32&15)); bias0 pre-folded.
template<bool ISBF>
__launch_bounds__(PGT, 1)
__global__ void pregemm_kernel(const int* __restrict__ tokens,
                               const void* __restrict__ emb,
                               const void* __restrict__ Wx0,
                               const void* __restrict__ bias,
                               __bf16* __restrict__ U,
                               const int* __restrict__ flag) {
  if ((*flag != 0) != ISBF) return;
  __shared__ __align__(16) __bf16 sA[8 * 4 * 64 * 8];
  __shared__ __align__(16) __bf16 lout[32768];

  const int tid = threadIdx.x, lane = tid & 63, wv = tid >> 6;
  const int m = lane & 15, kc = lane >> 4;
  const int g = blockIdx.x / 10, tc = blockIdx.x % 10;
  const int B0 = g * 16, T0 = tc * 8;

  for (int q = tid; q < 128 * 32; q += PGT) {
    int r = q >> 5, c = (q & 31) * 4;
    int tok = tokens[(B0 + (r >> 3)) * Tt + T0 + (r & 7)];
    float v0 = 0.f, v1 = 0.f, v2 = 0.f, v3 = 0.f;
    if (c < Ee) {
      if constexpr (ISBF) {
        bf16x4 t4 = *(const bf16x4*)((const __bf16*)emb + tok * Ee + c);
        v0 = (float)t4[0]; v1 = (float)t4[1]; v2 = (float)t4[2]; v3 = (float)t4[3];
      } else {
        f32x4 t4 = *(const f32x4*)((const float*)emb + tok * Ee + c);
        v0 = t4[0]; v1 = t4[1]; v2 = t4[2]; v3 = t4[3];
      }
    }
    __bf16* p = sA + (((r >> 4) * 4 + (c >> 5)) * 64 + ((c >> 3) & 3) * 16 + (r & 15)) * 8 + (c & 7);
    p[0] = (__bf16)v0; p[1] = (__bf16)v1; p[2] = (__bf16)v2; p[3] = (__bf16)v3;
  }

  bf16x8 fB[2][4];
  float bs[2];
  #pragma unroll
  for (int e = 0; e < 2; ++e) {
    const int col = wv * 32 + e * 16 + m;
    bs[e] = ldf<ISBF>(bias, col);
    #pragma unroll
    for (int s = 0; s < 4; ++s) {
      bf16x8 tr;
      #pragma unroll
      for (int j = 0; j < 8; ++j) {
        int k = s * 32 + kc * 8 + j;
        tr[j] = (k < Ee) ? (__bf16)ldf<ISBF>(Wx0, k * Uu + col) : (__bf16)0.f;
      }
      fB[e][s] = tr;
    }
  }
  __syncthreads();

  const int au = (kc * 16 + m) * 8;
  const int lr3 = lane >> 5;
  const int tb = ((lane >> 4) & 1) * 4;
  #pragma unroll
  for (int mt = 0; mt < 8; ++mt) {
    f32x4 a0 = {0.f,0.f,0.f,0.f}, a1 = {0.f,0.f,0.f,0.f};
    #pragma unroll
    for (int s = 0; s < 4; ++s) {
      bf16x8 a = *(const bf16x8*)(sA + (mt * 4 + s) * 512 + au);
      a0 = MFMA16(a, fB[0][s], a0);
      a1 = MFMA16(a, fB[1][s], a1);
    }
    int rr = mt * 2 + lr3;
    int rb_l = rr >> 3, r8 = rr & 7;
    int lane32 = ((r8 >> 2) << 4) + m;
    int i = r8 & 3;
    int e0 = (wv & 1) * 2;
    #pragma unroll
    for (int ii = 0; ii < 4; ++ii) {
      int base = (((tb + ii) * 2 + rb_l) * 128 + (wv >> 1) * 32 + lane32) * 16 + i;
      lout[base + e0 * 4]       = (__bf16)(a0[ii] + bs[0]);
      lout[base + (e0 + 1) * 4] = (__bf16)(a1[ii] + bs[1]);
    }
  }
  __syncthreads();

  for (int it = 0; it < 8; ++it) {
    int idx = (it * PGT + tid) * 8;
    int p = idx >> 11, w = idx & 2047;
    int t_l = p >> 1, rb_l = p & 1;
    size_t dst = ((size_t)((T0 + t_l) * 256 + (g * 2 + rb_l))) * 2048 + w;
    *(bf16x8*)(U + dst) = *(const bf16x8*)(lout + idx);
  }
}

// ---------------- persistent 2-layer RNN, fused single-barrier scan --------
// 8 waves x 2 col-tiles. Per step one phase computes h1_new(t) AND
// h0_new(t+1); h0_new(t) A-frags read once, feed @Wx1 and @Wh0.
template<bool ISBF>
__launch_bounds__(RNT, 2)
__global__ void rnn_kernel(const void* __restrict__ Wx1,
                           const void* __restrict__ Wh,
                           const void* __restrict__ bias,
                           const void* __restrict__ h0g,
                           const void* __restrict__ Wo,
                           const void* __restrict__ bo,
                           const __bf16* __restrict__ U,
                           void* __restrict__ out,
                           const int* __restrict__ flag) {
  if ((*flag != 0) != ISBF) return;

  __shared__ __align__(16) __bf16 s_h0[2 * HB];
  __shared__ __align__(16) __bf16 s_h1[2 * HB];

  const int tid = threadIdx.x, lane = tid & 63, wv = tid >> 6;  // wv 0..7
  const int m = lane & 15, kc = lane >> 4;
  const int rb = blockIdx.x, b0 = rb * BM;
  const int au = (kc * 8 + (m & 7)) * 8;   // A-read; lanes m>=8 broadcast row m-8

  for (int idx = tid; idx < BM * Uu; idx += RNT) {
    int r = idx >> 8, c = idx & 255;
    int off = (c >> 5) * HCH + (((c >> 3) & 3) * 8 + r) * 8 + (c & 7);
    s_h0[off] = (__bf16)ldf<ISBF>(h0g, (b0 + r) * Uu + c);
    s_h1[off] = (__bf16)ldf<ISBF>(h0g, Bb * Uu + (b0 + r) * Uu + c);
  }

  // persistent weight B-frags: 2 tiles x 3 matrices x 8 chunks = 192 VGPRs
  bf16x8 fWh0[2][8], fWx1f[2][8], fWh1[2][8];
  float b1v[2];
  #pragma unroll
  for (int e = 0; e < 2; ++e) {
    const int col = wv * 32 + e * 16 + m;
    b1v[e] = ldf<ISBF>(bias, Uu + col);
    #pragma unroll
    for (int s = 0; s < 8; ++s) {
      const int kb = s * 32 + kc * 8;
      bf16x8 t0, t1, t2;
      #pragma unroll
      for (int j = 0; j < 8; ++j) {
        t0[j] = (__bf16)ldf<ISBF>(Wh,  (kb + j) * Uu + col);
        t1[j] = (__bf16)ldf<ISBF>(Wx1, (kb + j) * Uu + col);
        t2[j] = (__bf16)ldf<ISBF>(Wh,  Uu * Uu + (kb + j) * Uu + col);
      }
      fWh0[e][s] = t0; fWx1f[e][s] = t1; fWh1[e][s] = t2;
    }
  }

  // u fetch address: lane (wv,kc,m) needs old-layout tid32 = (wv>>1)*32 + (kc&1)*16 + m,
  // slots (wv&1)*8 .. +7  (one bf16x8 per lane).
  const int tid32u = (wv >> 1) * 32 + ((kc & 1) * 16) + m;
  const __bf16* Ubase = U + (size_t)tid32u * 16 + (wv & 1) * 8 + (size_t)rb * 2048;
  // u(t) at Ubase + t*256*2048

  const int kc2 = m >> 3, j2 = m & 7, rb2 = (lane >> 4) * 4;  // write decomp (lane<32)

  bf16x8 u0 = *(const bf16x8*)(Ubase);   // u(0)

  __syncthreads();

  // ---- prologue: h0_new(0) = tanh(u(0) + h0_init@Wh0) -> s_h0[1] ----
  {
    f32x4 d0 = {(float)u0[0], (float)u0[1], (float)u0[2], (float)u0[3]};
    f32x4 d1 = {(float)u0[4], (float)u0[5], (float)u0[6], (float)u0[7]};
    const __bf16* hb = s_h0 + au;
    #pragma unroll
    for (int s = 0; s < 8; ++s) {
      bf16x8 a = *(const bf16x8*)(hb + s * HCH);
      d0 = MFMA16(a, fWh0[0][s], d0);
      d1 = MFMA16(a, fWh0[1][s], d1);
    }
    u0 = *(const bf16x8*)(Ubase + (size_t)1 * 256 * 2048);  // prefetch u(1)
    if (lane < 32) {
      #pragma unroll
      for (int e = 0; e < 2; ++e) {
        __bf16* wp = s_h0 + HB + wv * HCH + ((e * 2 + kc2) * 8 + rb2) * 8 + j2;
        f32x4& dd = e ? d1 : d0;
        #pragma unroll
        for (int ii = 0; ii < 4; ++ii)
          wp[ii * 8] = (__bf16)fast_tanh(dd[ii]);
      }
    }
    __syncthreads();
  }

  for (int t = 0; t < Tt; ++t) {
    const int p = t & 1, pn = p ^ 1;
    // prefetch u(t+2) early; consumed next iteration
    int tf = (t + 2 < Tt) ? t + 2 : Tt - 1;
    bf16x8 un = *(const bf16x8*)(Ubase + (size_t)tf * 256 * 2048);

    // 6 chains: B=h0n@Wx1, C=h1@Wh1 (sum -> h1_new), D=u+h0n@Wh0 (-> h0_next)
    f32x4 cB0 = {0.f,0.f,0.f,0.f}, cB1 = {0.f,0.f,0.f,0.f};
    f32x4 cC0 = {0.f,0.f,0.f,0.f}, cC1 = {0.f,0.f,0.f,0.f};
    f32x4 cD0 = {(float)u0[0], (float)u0[1], (float)u0[2], (float)u0[3]};
    f32x4 cD1 = {(float)u0[4], (float)u0[5], (float)u0[6], (float)u0[7]};
    {
      const __bf16* h0b = s_h0 + pn * HB + au;   // h0_new(t)
      const __bf16* h1b = s_h1 + p * HB + au;    // h1(t)
      #pragma unroll
      for (int s = 0; s < 8; ++s) {
        bf16x8 a0 = *(const bf16x8*)(h0b + s * HCH);
        bf16x8 a1 = *(const bf16x8*)(h1b + s * HCH);
        cB0 = MFMA16(a0, fWx1f[0][s], cB0);
        cB1 = MFMA16(a0, fWx1f[1][s], cB1);
        cD0 = MFMA16(a0, fWh0[0][s], cD0);
        cD1 = MFMA16(a0, fWh0[1][s], cD1);
        cC0 = MFMA16(a1, fWh1[0][s], cC0);
        cC1 = MFMA16(a1, fWh1[1][s], cC1);
      }
    }
    if (lane < 32) {
      #pragma unroll
      for (int e = 0; e < 2; ++e) {
        const int toff = wv * HCH + ((e * 2 + kc2) * 8 + rb2) * 8 + j2;
        __bf16* wp1 = s_h1 + pn * HB + toff;     // h1_new(t)
        __bf16* wp0 = s_h0 + p * HB + toff;      // h0_new(t+1)
        f32x4 hb1, hd0;
        if (e) { hb1 = cB1 + cC1; hd0 = cD1; } else { hb1 = cB0 + cC0; hd0 = cD0; }
        #pragma unroll
        for (int ii = 0; ii < 4; ++ii) {
          wp1[ii * 8] = (__bf16)fast_tanh(hb1[ii] + b1v[e]);
          wp0[ii * 8] = (__bf16)fast_tanh(hd0[ii]);
        }
      }
    }
    u0 = un;
    __syncthreads();
  }

  // ---- epilogue: sigmoid(h1_new(79) @ Wo + bo); lives in s_h1[0] ----
  if (tid < 256) {
    const int r = tid >> 5, q = tid & 31;
    const __bf16* hp = s_h1 + (q >> 2) * HCH + ((q & 3) * 8 + r) * 8;
    bf16x8 hv = *(const bf16x8*)hp;
    float part = 0.f;
    #pragma unroll
    for (int j = 0; j < 8; ++j) part += (float)hv[j] * ldf<ISBF>(Wo, q * 8 + j);
    #pragma unroll
    for (int o = 16; o >= 1; o >>= 1) part += __shfl_down(part, o, 32);
    if (q == 0) {
      float z = part + ldf<ISBF>(bo, 0);
      float sg = 1.f / (1.f + __expf(-z));
      if constexpr (ISBF) ((__bf16*)out)[b0 + r] = (__bf16)sg;
      else                ((float*)out)[b0 + r]  = sg;
    }
  }
}

extern "C" void kernel_launch(void* const* d_in, const int* in_sizes, int n_in,
                              void* d_out, int out_size, void* d_ws, size_t ws_size,
                              hipStream_t stream) {
  const int*  tokens = (const int*)d_in[0];
  const void* emb = d_in[1];
  const void* Wx0 = d_in[2];
  const void* Wx1 = d_in[3];
  const void* Wh  = d_in[4];
  const void* b   = d_in[5];
  const void* h0  = d_in[6];
  const void* Wo  = d_in[7];
  const void* bo  = d_in[8];

  int* flag = (int*)d_ws;
  __bf16* U = (__bf16*)((char*)d_ws + 256);
  const size_t needU = 256 + (size_t)Tt * 256 * 128 * 16 * sizeof(__bf16);  // ~84 MB
  if (ws_size < needU) return;

  detect_kernel<<<1, 64, 0, stream>>>(Wh, flag);
  pregemm_kernel<true ><<<dim3(128 * 10), dim3(PGT), 0, stream>>>(tokens, emb, Wx0, b, U, flag);
  pregemm_kernel<false><<<dim3(128 * 10), dim3(PGT), 0, stream>>>(tokens, emb, Wx0, b, U, flag);
  rnn_kernel<true ><<<dim3(Bb / BM), dim3(RNT), 0, stream>>>(Wx1, Wh, b, h0, Wo, bo, U, d_out, flag);
  rnn_kernel<false><<<dim3(Bb / BM), dim3(RNT), 0, stream>>>(Wx1, Wh, b, h0, Wo, bo, U, d_out, flag);
}

// Round 6
// 311.642 us; speedup vs baseline: 1.3411x; 1.1241x over previous
//
#include <hip/hip_runtime.h>
#include <hip/hip_bf16.h>

typedef __bf16 bf16x8 __attribute__((ext_vector_type(8)));
typedef __bf16 bf16x4 __attribute__((ext_vector_type(4)));
typedef float  f32x4  __attribute__((ext_vector_type(4)));

#define MFMA16(a,b,c) __builtin_amdgcn_mfma_f32_16x16x32_bf16((a),(b),(c),0,0,0)

// Opaque pin: forces the fragment to stay VGPR-resident (asm outputs are not
// rematerializable, so the compiler cannot re-load weights from L2 per step).
#define PIN8(v8) do { f32x4 _t = __builtin_bit_cast(f32x4, (v8)); \
                      asm volatile("" : "+v"(_t)); \
                      (v8) = __builtin_bit_cast(bf16x8, _t); } while (0)

constexpr int Bb = 2048, Tt = 80, Ee = 100, Uu = 256;
constexpr int BM = 8;          // batch rows per rnn block
constexpr int RNT = 512;       // rnn: 8 waves
constexpr int PGT = 512;       // pregemm: 8 waves
constexpr int HCH = 256;       // elems per k-chunk (32 k x 8 rows)
constexpr int HB = 8 * HCH;    // one h buffer

template<bool ISBF>
__device__ __forceinline__ float ldf(const void* p, int i) {
  if constexpr (ISBF) return (float)((const __bf16*)p)[i];
  else                return ((const float*)p)[i];
}

__device__ __forceinline__ float fast_tanh(float x) {
  float e = __expf(2.f * x);
  return 1.f - 2.f / (e + 1.f);
}

__global__ void detect_kernel(const void* wh, int* flag) {
  __shared__ int cnt;
  if (threadIdx.x == 0) cnt = 0;
  __syncthreads();
  const unsigned short* u = (const unsigned short*)wh;
  int c = 0;
  for (int i = threadIdx.x; i < 256; i += 64) {
    unsigned short h = u[2 * i];
    int ex = (h >> 7) & 0xFF;
    if (ex >= 135 || (ex >= 1 && ex <= 95)) c++;
  }
  atomicAdd(&cnt, c);
  __syncthreads();
  if (threadIdx.x == 0) *flag = (cnt < 64) ? 1 : 0;
}

// ---------------- pre-GEMM (R3/R4 known-good) ------------------------------
// U layout: U[t][rb][tid32][16] bf16; slot = e*4+i where (row = ((tid32>>4)&1)*4+i,
// col = (tid32>>5)*64 + e*16 + (tid32&15)); bias0 pre-folded.
template<bool ISBF>
__launch_bounds__(PGT, 1)
__global__ void pregemm_kernel(const int* __restrict__ tokens,
                               const void* __restrict__ emb,
                               const void* __restrict__ Wx0,
                               const void* __restrict__ bias,
                               __bf16* __restrict__ U,
                               const int* __restrict__ flag) {
  if ((*flag != 0) != ISBF) return;
  __shared__ __align__(16) __bf16 sA[8 * 4 * 64 * 8];
  __shared__ __align__(16) __bf16 lout[32768];

  const int tid = threadIdx.x, lane = tid & 63, wv = tid >> 6;
  const int m = lane & 15, kc = lane >> 4;
  const int g = blockIdx.x / 10, tc = blockIdx.x % 10;
  const int B0 = g * 16, T0 = tc * 8;

  for (int q = tid; q < 128 * 32; q += PGT) {
    int r = q >> 5, c = (q & 31) * 4;
    int tok = tokens[(B0 + (r >> 3)) * Tt + T0 + (r & 7)];
    float v0 = 0.f, v1 = 0.f, v2 = 0.f, v3 = 0.f;
    if (c < Ee) {
      if constexpr (ISBF) {
        bf16x4 t4 = *(const bf16x4*)((const __bf16*)emb + tok * Ee + c);
        v0 = (float)t4[0]; v1 = (float)t4[1]; v2 = (float)t4[2]; v3 = (float)t4[3];
      } else {
        f32x4 t4 = *(const f32x4*)((const float*)emb + tok * Ee + c);
        v0 = t4[0]; v1 = t4[1]; v2 = t4[2]; v3 = t4[3];
      }
    }
    __bf16* p = sA + (((r >> 4) * 4 + (c >> 5)) * 64 + ((c >> 3) & 3) * 16 + (r & 15)) * 8 + (c & 7);
    p[0] = (__bf16)v0; p[1] = (__bf16)v1; p[2] = (__bf16)v2; p[3] = (__bf16)v3;
  }

  bf16x8 fB[2][4];
  float bs[2];
  #pragma unroll
  for (int e = 0; e < 2; ++e) {
    const int col = wv * 32 + e * 16 + m;
    bs[e] = ldf<ISBF>(bias, col);
    #pragma unroll
    for (int s = 0; s < 4; ++s) {
      bf16x8 tr;
      #pragma unroll
      for (int j = 0; j < 8; ++j) {
        int k = s * 32 + kc * 8 + j;
        tr[j] = (k < Ee) ? (__bf16)ldf<ISBF>(Wx0, k * Uu + col) : (__bf16)0.f;
      }
      fB[e][s] = tr;
    }
  }
  __syncthreads();

  const int au = (kc * 16 + m) * 8;
  const int lr3 = lane >> 5;
  const int tb = ((lane >> 4) & 1) * 4;
  #pragma unroll
  for (int mt = 0; mt < 8; ++mt) {
    f32x4 a0 = {0.f,0.f,0.f,0.f}, a1 = {0.f,0.f,0.f,0.f};
    #pragma unroll
    for (int s = 0; s < 4; ++s) {
      bf16x8 a = *(const bf16x8*)(sA + (mt * 4 + s) * 512 + au);
      a0 = MFMA16(a, fB[0][s], a0);
      a1 = MFMA16(a, fB[1][s], a1);
    }
    int rr = mt * 2 + lr3;
    int rb_l = rr >> 3, r8 = rr & 7;
    int lane32 = ((r8 >> 2) << 4) + m;
    int i = r8 & 3;
    int e0 = (wv & 1) * 2;
    #pragma unroll
    for (int ii = 0; ii < 4; ++ii) {
      int base = (((tb + ii) * 2 + rb_l) * 128 + (wv >> 1) * 32 + lane32) * 16 + i;
      lout[base + e0 * 4]       = (__bf16)(a0[ii] + bs[0]);
      lout[base + (e0 + 1) * 4] = (__bf16)(a1[ii] + bs[1]);
    }
  }
  __syncthreads();

  for (int it = 0; it < 8; ++it) {
    int idx = (it * PGT + tid) * 8;
    int p = idx >> 11, w = idx & 2047;
    int t_l = p >> 1, rb_l = p & 1;
    size_t dst = ((size_t)((T0 + t_l) * 256 + (g * 2 + rb_l))) * 2048 + w;
    *(bf16x8*)(U + dst) = *(const bf16x8*)(lout + idx);
  }
}

// ---------------- persistent 2-layer RNN, fused single-barrier scan --------
// 8 waves x 2 col-tiles; weights pinned VGPR-resident via PIN8.
template<bool ISBF>
__launch_bounds__(RNT, 2)
__global__ void rnn_kernel(const void* __restrict__ Wx1,
                           const void* __restrict__ Wh,
                           const void* __restrict__ bias,
                           const void* __restrict__ h0g,
                           const void* __restrict__ Wo,
                           const void* __restrict__ bo,
                           const __bf16* __restrict__ U,
                           void* __restrict__ out,
                           const int* __restrict__ flag) {
  if ((*flag != 0) != ISBF) return;

  __shared__ __align__(16) __bf16 s_h0[2 * HB];
  __shared__ __align__(16) __bf16 s_h1[2 * HB];

  const int tid = threadIdx.x, lane = tid & 63, wv = tid >> 6;  // wv 0..7
  const int m = lane & 15, kc = lane >> 4;
  const int rb = blockIdx.x, b0 = rb * BM;
  const int au = (kc * 8 + (m & 7)) * 8;   // A-read; lanes m>=8 broadcast row m-8

  for (int idx = tid; idx < BM * Uu; idx += RNT) {
    int r = idx >> 8, c = idx & 255;
    int off = (c >> 5) * HCH + (((c >> 3) & 3) * 8 + r) * 8 + (c & 7);
    s_h0[off] = (__bf16)ldf<ISBF>(h0g, (b0 + r) * Uu + c);
    s_h1[off] = (__bf16)ldf<ISBF>(h0g, Bb * Uu + (b0 + r) * Uu + c);
  }

  // persistent weight B-frags: 2 tiles x 3 matrices x 8 chunks = 192 VGPRs
  bf16x8 fWh0[2][8], fWx1f[2][8], fWh1[2][8];
  float b1v[2];
  #pragma unroll
  for (int e = 0; e < 2; ++e) {
    const int col = wv * 32 + e * 16 + m;
    b1v[e] = ldf<ISBF>(bias, Uu + col);
    #pragma unroll
    for (int s = 0; s < 8; ++s) {
      const int kb = s * 32 + kc * 8;
      bf16x8 t0, t1, t2;
      #pragma unroll
      for (int j = 0; j < 8; ++j) {
        t0[j] = (__bf16)ldf<ISBF>(Wh,  (kb + j) * Uu + col);
        t1[j] = (__bf16)ldf<ISBF>(Wx1, (kb + j) * Uu + col);
        t2[j] = (__bf16)ldf<ISBF>(Wh,  Uu * Uu + (kb + j) * Uu + col);
      }
      fWh0[e][s] = t0; fWx1f[e][s] = t1; fWh1[e][s] = t2;
    }
  }
  // pin all 24 fragments -> not rematerializable, must stay in VGPRs
  #pragma unroll
  for (int e = 0; e < 2; ++e) {
    #pragma unroll
    for (int s = 0; s < 8; ++s) {
      PIN8(fWh0[e][s]); PIN8(fWx1f[e][s]); PIN8(fWh1[e][s]);
    }
  }

  // u fetch: lane needs old-layout tid32 = (wv>>1)*32 + (kc&1)*16 + m,
  // slots (wv&1)*8 .. +7 (one bf16x8 per lane)
  const int tid32u = (wv >> 1) * 32 + ((kc & 1) * 16) + m;
  const __bf16* Ubase = U + (size_t)tid32u * 16 + (wv & 1) * 8 + (size_t)rb * 2048;

  const int kc2 = m >> 3, j2 = m & 7, rb2 = (lane >> 4) * 4;  // write decomp (lane<32)

  bf16x8 u0 = *(const bf16x8*)(Ubase);   // u(0)

  __syncthreads();

  // ---- prologue: h0_new(0) = tanh(u(0) + h0_init@Wh0) -> s_h0[1] ----
  {
    f32x4 d0 = {(float)u0[0], (float)u0[1], (float)u0[2], (float)u0[3]};
    f32x4 d1 = {(float)u0[4], (float)u0[5], (float)u0[6], (float)u0[7]};
    const __bf16* hb = s_h0 + au;
    #pragma unroll
    for (int s = 0; s < 8; ++s) {
      bf16x8 a = *(const bf16x8*)(hb + s * HCH);
      d0 = MFMA16(a, fWh0[0][s], d0);
      d1 = MFMA16(a, fWh0[1][s], d1);
    }
    u0 = *(const bf16x8*)(Ubase + (size_t)1 * 256 * 2048);  // prefetch u(1)
    if (lane < 32) {
      #pragma unroll
      for (int e = 0; e < 2; ++e) {
        __bf16* wp = s_h0 + HB + wv * HCH + ((e * 2 + kc2) * 8 + rb2) * 8 + j2;
        f32x4& dd = e ? d1 : d0;
        #pragma unroll
        for (int ii = 0; ii < 4; ++ii)
          wp[ii * 8] = (__bf16)fast_tanh(dd[ii]);
      }
    }
    __syncthreads();
  }

  for (int t = 0; t < Tt; ++t) {
    const int p = t & 1, pn = p ^ 1;
    int tf = (t + 2 < Tt) ? t + 2 : Tt - 1;
    bf16x8 un = *(const bf16x8*)(Ubase + (size_t)tf * 256 * 2048);

    // 6 chains: B=h0n@Wx1, C=h1@Wh1 (sum -> h1_new), D=u+h0n@Wh0 (-> h0_next)
    f32x4 cB0 = {0.f,0.f,0.f,0.f}, cB1 = {0.f,0.f,0.f,0.f};
    f32x4 cC0 = {0.f,0.f,0.f,0.f}, cC1 = {0.f,0.f,0.f,0.f};
    f32x4 cD0 = {(float)u0[0], (float)u0[1], (float)u0[2], (float)u0[3]};
    f32x4 cD1 = {(float)u0[4], (float)u0[5], (float)u0[6], (float)u0[7]};
    {
      const __bf16* h0b = s_h0 + pn * HB + au;   // h0_new(t)
      const __bf16* h1b = s_h1 + p * HB + au;    // h1(t)
      #pragma unroll
      for (int s = 0; s < 8; ++s) {
        bf16x8 a0 = *(const bf16x8*)(h0b + s * HCH);
        bf16x8 a1 = *(const bf16x8*)(h1b + s * HCH);
        cB0 = MFMA16(a0, fWx1f[0][s], cB0);
        cB1 = MFMA16(a0, fWx1f[1][s], cB1);
        cD0 = MFMA16(a0, fWh0[0][s], cD0);
        cD1 = MFMA16(a0, fWh0[1][s], cD1);
        cC0 = MFMA16(a1, fWh1[0][s], cC0);
        cC1 = MFMA16(a1, fWh1[1][s], cC1);
      }
    }
    if (lane < 32) {
      #pragma unroll
      for (int e = 0; e < 2; ++e) {
        const int toff = wv * HCH + ((e * 2 + kc2) * 8 + rb2) * 8 + j2;
        __bf16* wp1 = s_h1 + pn * HB + toff;     // h1_new(t)
        __bf16* wp0 = s_h0 + p * HB + toff;      // h0_new(t+1)
        f32x4 hb1, hd0;
        if (e) { hb1 = cB1 + cC1; hd0 = cD1; } else { hb1 = cB0 + cC0; hd0 = cD0; }
        #pragma unroll
        for (int ii = 0; ii < 4; ++ii) {
          wp1[ii * 8] = (__bf16)fast_tanh(hb1[ii] + b1v[e]);
          wp0[ii * 8] = (__bf16)fast_tanh(hd0[ii]);
        }
      }
    }
    u0 = un;
    __syncthreads();
  }

  // ---- epilogue: sigmoid(h1_new(79) @ Wo + bo); lives in s_h1[0] ----
  if (tid < 256) {
    const int r = tid >> 5, q = tid & 31;
    const __bf16* hp = s_h1 + (q >> 2) * HCH + ((q & 3) * 8 + r) * 8;
    bf16x8 hv = *(const bf16x8*)hp;
    float part = 0.f;
    #pragma unroll
    for (int j = 0; j < 8; ++j) part += (float)hv[j] * ldf<ISBF>(Wo, q * 8 + j);
    #pragma unroll
    for (int o = 16; o >= 1; o >>= 1) part += __shfl_down(part, o, 32);
    if (q == 0) {
      float z = part + ldf<ISBF>(bo, 0);
      float sg = 1.f / (1.f + __expf(-z));
      if constexpr (ISBF) ((__bf16*)out)[b0 + r] = (__bf16)sg;
      else                ((float*)out)[b0 + r]  = sg;
    }
  }
}

extern "C" void kernel_launch(void* const* d_in, const int* in_sizes, int n_in,
                              void* d_out, int out_size, void* d_ws, size_t ws_size,
                              hipStream_t stream) {
  const int*  tokens = (const int*)d_in[0];
  const void* emb = d_in[1];
  const void* Wx0 = d_in[2];
  const void* Wx1 = d_in[3];
  const void* Wh  = d_in[4];
  const void* b   = d_in[5];
  const void* h0  = d_in[6];
  const void* Wo  = d_in[7];
  const void* bo  = d_in[8];

  int* flag = (int*)d_ws;
  __bf16* U = (__bf16*)((char*)d_ws + 256);
  const size_t needU = 256 + (size_t)Tt * 256 * 2048 * sizeof(__bf16);  // ~84 MB
  if (ws_size < needU) return;

  detect_kernel<<<1, 64, 0, stream>>>(Wh, flag);
  pregemm_kernel<true ><<<dim3(128 * 10), dim3(PGT), 0, stream>>>(tokens, emb, Wx0, b, U, flag);
  pregemm_kernel<false><<<dim3(128 * 10), dim3(PGT), 0, stream>>>(tokens, emb, Wx0, b, U, flag);
  rnn_kernel<true ><<<dim3(Bb / BM), dim3(RNT), 0, stream>>>(Wx1, Wh, b, h0, Wo, bo, U, d_out, flag);
  rnn_kernel<false><<<dim3(Bb / BM), dim3(RNT), 0, stream>>>(Wx1, Wh, b, h0, Wo, bo, U, d_out, flag);
}